// Round 8
// baseline (550.010 us; speedup 1.0000x reference)
//
#include <hip/hip_runtime.h>
#include <hip/hip_bf16.h>
#include <hip/hip_cooperative_groups.h>

namespace cg = cooperative_groups;

// Problem constants (CeptaBlock): B=4,T=2048,D=2048,P=512,K=16,ALPHA=4,R=32
#define B_ 4
#define T_ 2048
#define D_ 2048
#define P_ 512
#define K_ 16
#define ALPHA_ 4
#define R_ 32
#define NE_ 409        // int(0.8*512) -> excitatory count
#define EPS_ 1e-6f
#define G_ 4           // tokens per group
#define NGRP_ (B_ * T_ / G_)   // 2048 token-groups

typedef unsigned short u16;
typedef unsigned int u32;

__device__ __forceinline__ float sigmoidf_(float x) {
  return 1.0f / (1.0f + __expf(-x));
}
__device__ __forceinline__ float bfb2f(u32 u) {
  return __uint_as_float(u << 16);
}
// fp32 -> bf16 bits, round-to-nearest-even (header-independent)
__device__ __forceinline__ u16 f2bfb(float f) {
  u32 bits = __float_as_uint(f);
  u32 lsb = (bits >> 16) & 1u;
  bits += 0x7fffu + lsb;
  return (u16)(bits >> 16);
}

struct SmemP1 {
  u16 h[G_ * D_];          // 16 KB
  u32 ftw[G_ * P_];        // 8 KB packed (f | t<<16)
  float zp[G_][R_][4];     // 2 KB
  float lp[G_][R_][4];     // 2 KB
  float red[G_][4];
};
struct SmemP3 {
  u16 h[G_ * D_];          // 16 KB
  float Sl[G_][R_];        // 512 B
  float red[G_][4];
};
union SmemU { SmemP1 p1; SmemP3 p3; };   // ~28.1 KB

// ---------------- phase 1 device fn: rmsnorm1 + gather + perceptron + z/lam ----------------
__device__ __forceinline__ void phase1_dev(
    SmemP1& sm, int gi, int tid,
    const float* __restrict__ x, const float* __restrict__ g1,
    const int* __restrict__ idx_s, const float* __restrict__ wg_s,
    const float* __restrict__ Wp_s, const float* __restrict__ U,
    const float* __restrict__ Wgt, const float* __restrict__ bg,
    u32* __restrict__ ftg, float* __restrict__ z, float* __restrict__ lam) {
  int token0 = gi * G_;
  int b = token0 >> 11;
  int t0 = token0 & (T_ - 1);
  int p0 = 2 * tid, p1 = p0 + 1;

  float gv[8];
  {
    const float4* gp = reinterpret_cast<const float4*>(g1 + tid * 8);
    *reinterpret_cast<float4*>(&gv[0]) = gp[0];
    *reinterpret_cast<float4*>(&gv[4]) = gp[1];
  }
  float xv[G_][8];
#pragma unroll
  for (int tok = 0; tok < G_; tok++) {
    const float4* xp = reinterpret_cast<const float4*>(x + (size_t)(token0 + tok) * D_ + tid * 8);
    *reinterpret_cast<float4*>(&xv[tok][0]) = xp[0];
    *reinterpret_cast<float4*>(&xv[tok][4]) = xp[1];
    float ss = 0;
#pragma unroll
    for (int i = 0; i < 8; i++) ss += xv[tok][i] * xv[tok][i];
#pragma unroll
    for (int off = 32; off; off >>= 1) ss += __shfl_down(ss, off);
    if ((tid & 63) == 0) sm.red[tok][tid >> 6] = ss;
  }
  __syncthreads();
#pragma unroll
  for (int tok = 0; tok < G_; tok++) {
    float inv = rsqrtf((sm.red[tok][0] + sm.red[tok][1] + sm.red[tok][2] + sm.red[tok][3]) * (1.0f / D_) + EPS_);
    u16 tmp[8];
#pragma unroll
    for (int i = 0; i < 8; i++) tmp[i] = f2bfb(xv[tok][i] * inv * gv[i]);
    *reinterpret_cast<uint4*>(&sm.h[tok * D_ + tid * 8]) = *reinterpret_cast<const uint4*>(tmp);
  }
  // gather weights + local quant scalars (issued while barrier drains)
  union { int4 v[4]; int s[16]; } iu0, iu1;
  union { float4 v[4]; float s[16]; } wu0, wu1;
  {
    const int4* ip0 = reinterpret_cast<const int4*>(idx_s + p0 * K_);
    const int4* ip1 = reinterpret_cast<const int4*>(idx_s + p1 * K_);
    const float4* wp0 = reinterpret_cast<const float4*>(wg_s + p0 * K_);
    const float4* wp1 = reinterpret_cast<const float4*>(wg_s + p1 * K_);
#pragma unroll
    for (int q = 0; q < 4; q++) { iu0.v[q] = ip0[q]; iu1.v[q] = ip1[q]; wu0.v[q] = wp0[q]; wu1.v[q] = wp1[q]; }
  }
  float wq0, wq1;
  {
    const float4* w0 = reinterpret_cast<const float4*>(Wp_s + p0 * K_);
    const float4* w1 = reinterpret_cast<const float4*>(Wp_s + p1 * K_);
    float a0 = 0, a1 = 0;
#pragma unroll
    for (int q = 0; q < 4; q++) {
      float4 v0 = w0[q], v1 = w1[q];
      a0 += fabsf(v0.x) + fabsf(v0.y) + fabsf(v0.z) + fabsf(v0.w);
      a1 += fabsf(v1.x) + fabsf(v1.y) + fabsf(v1.z) + fabsf(v1.w);
    }
    wq0 = ((p0 < NE_) ? 1.0f : -1.0f) * a0 * (1.0f / K_);
    wq1 = ((p1 < NE_) ? 1.0f : -1.0f) * a1 * (1.0f / K_);
  }
  __syncthreads();

  // perceptron
#pragma unroll
  for (int tok = 0; tok < G_; tok++) {
    float a0 = 0, a1 = 0;
#pragma unroll
    for (int k = 0; k < K_; k++) {
      a0 += bfb2f(sm.h[tok * D_ + iu0.s[k]]) * wu0.s[k];
      a1 += bfb2f(sm.h[tok * D_ + iu1.s[k]]) * wu1.s[k];
    }
    float u0 = wq0 * a0, u1 = wq1 * a1;
    float f0 = sigmoidf_(u0), f1 = sigmoidf_(u1);
    u32 pk0 = (u32)f2bfb(f0) | ((u32)f2bfb(f0 * u0) << 16);
    u32 pk1 = (u32)f2bfb(f1) | ((u32)f2bfb(f1 * u1) << 16);
    *reinterpret_cast<uint2*>(&sm.ftw[tok * P_ + p0]) = make_uint2(pk0, pk1);
    ftg[(size_t)(token0 + tok) * 256 + tid] = (u32)f2bfb(f0) | ((u32)f2bfb(f1) << 16);
  }
  __syncthreads();

  // z = t@U, lam = sigmoid(f@Wgate + bg)
  int r = tid & 31, grp = tid >> 5;
  float zs[G_], ls[G_];
#pragma unroll
  for (int tok = 0; tok < G_; tok++) { zs[tok] = 0; ls[tok] = 0; }
  int pbase = grp * 64;
#pragma unroll 8
  for (int pp = 0; pp < 64; pp++) {
    int p = pbase + pp;
    float uu = U[p * R_ + r];
    float ww = Wgt[p * R_ + r];
#pragma unroll
    for (int tok = 0; tok < G_; tok++) {
      u32 v = sm.ftw[tok * P_ + p];
      zs[tok] += bfb2f(v >> 16) * uu;
      ls[tok] += bfb2f(v & 0xffffu) * ww;
    }
  }
#pragma unroll
  for (int tok = 0; tok < G_; tok++) {
    zs[tok] += __shfl_down(zs[tok], 32);
    ls[tok] += __shfl_down(ls[tok], 32);
  }
  int wid = tid >> 6;
  if ((tid & 63) < 32) {
#pragma unroll
    for (int tok = 0; tok < G_; tok++) {
      sm.zp[tok][r][wid] = zs[tok];
      sm.lp[tok][r][wid] = ls[tok];
    }
  }
  __syncthreads();
  if (tid < R_) {
    float bgr = bg[tid];
    float z4[G_], l4[G_];
#pragma unroll
    for (int tok = 0; tok < G_; tok++) {
      float zz = sm.zp[tok][tid][0] + sm.zp[tok][tid][1] + sm.zp[tok][tid][2] + sm.zp[tok][tid][3];
      float ll = sm.lp[tok][tid][0] + sm.lp[tok][tid][1] + sm.lp[tok][tid][2] + sm.lp[tok][tid][3];
      z4[tok] = zz;
      l4[tok] = sigmoidf_(ll + bgr);
    }
    size_t o = ((size_t)(b * R_ + tid)) * T_ + t0;
    *reinterpret_cast<float4*>(&z[o]) = *reinterpret_cast<const float4*>(z4);
    *reinterpret_cast<float4*>(&lam[o]) = *reinterpret_cast<const float4*>(l4);
  }
  __syncthreads();
}

// ---------------- scan device fn (wave 0 of the block) ----------------
__device__ __forceinline__ void scan_dev(
    int br, int tid,
    const float* __restrict__ z, const float* __restrict__ lam,
    const float* __restrict__ state, float* __restrict__ S,
    float* __restrict__ out_state) {
  if (tid >= 64) return;
  int lane = tid;
  const float* zr = z + (size_t)br * T_ + lane * 32;
  const float* lr = lam + (size_t)br * T_ + lane * 32;
  float zb[32], lb[32];
#pragma unroll
  for (int i = 0; i < 32; i += 4) {
    *reinterpret_cast<float4*>(&zb[i]) = *reinterpret_cast<const float4*>(&zr[i]);
    *reinterpret_cast<float4*>(&lb[i]) = *reinterpret_cast<const float4*>(&lr[i]);
  }
  float A = 1.0f, Z = 0.0f;
#pragma unroll
  for (int i = 0; i < 32; i++) { Z = lb[i] * Z + zb[i]; A *= lb[i]; }
  for (int off = 1; off < 64; off <<= 1) {
    float Ap = __shfl_up(A, off);
    float Zp = __shfl_up(Z, off);
    if (lane >= off) { Z = A * Zp + Z; A = A * Ap; }
  }
  float s0 = state[br];
  float Ae = __shfl_up(A, 1);
  float Ze = __shfl_up(Z, 1);
  float s = (lane == 0) ? s0 : (Ae * s0 + Ze);
  float sb[32];
#pragma unroll
  for (int i = 0; i < 32; i++) { s = lb[i] * s + zb[i]; sb[i] = s; }
  float* Sr = S + (size_t)br * T_ + lane * 32;
#pragma unroll
  for (int i = 0; i < 32; i += 4)
    *reinterpret_cast<float4*>(&Sr[i]) = *reinterpret_cast<const float4*>(&sb[i]);
  if (lane == 63) out_state[br] = s;
}

// ---------------- phase 3 device fn: tilde + residual + rmsnorm2 + MLP + out ----------------
__device__ __forceinline__ void phase3_dev(
    SmemP3& sm, int gi, int tid,
    const float* __restrict__ x, const float* __restrict__ g2,
    const int* __restrict__ idx_m, const float* __restrict__ wg_m,
    const float* __restrict__ Wo_s, const float* __restrict__ Wp_m,
    const float* __restrict__ Wo_m, const float* __restrict__ V,
    const float* __restrict__ S, const u32* __restrict__ ftg,
    float* __restrict__ out) {
  int token0 = gi * G_;
  int b = token0 >> 11;
  int t0 = token0 & (T_ - 1);
  int p0 = 2 * tid, p1 = p0 + 1;

  if (tid < G_ * R_) {
    int tok = tid >> 5, rr = tid & 31;
    sm.Sl[tok][rr] = S[((size_t)(b * R_ + rr)) * T_ + t0 + tok];
  }

  float sgn0 = (p0 < NE_) ? 1.0f : -1.0f;
  float sgn1 = (p1 < NE_) ? 1.0f : -1.0f;
  float fo_s0, fo_s1, fo_m0, fo_m1, wq_m0, wq_m1;
  {
    float4 c0 = *reinterpret_cast<const float4*>(Wo_s + p0 * ALPHA_);
    float4 c1 = *reinterpret_cast<const float4*>(Wo_s + p1 * ALPHA_);
    float4 d0 = *reinterpret_cast<const float4*>(Wo_m + p0 * ALPHA_);
    float4 d1 = *reinterpret_cast<const float4*>(Wo_m + p1 * ALPHA_);
    fo_s0 = sgn0 * (fabsf(c0.x) + fabsf(c0.y) + fabsf(c0.z) + fabsf(c0.w)) * (1.0f / ALPHA_);
    fo_s1 = sgn1 * (fabsf(c1.x) + fabsf(c1.y) + fabsf(c1.z) + fabsf(c1.w)) * (1.0f / ALPHA_);
    fo_m0 = sgn0 * (fabsf(d0.x) + fabsf(d0.y) + fabsf(d0.z) + fabsf(d0.w)) * (1.0f / ALPHA_);
    fo_m1 = sgn1 * (fabsf(d1.x) + fabsf(d1.y) + fabsf(d1.z) + fabsf(d1.w)) * (1.0f / ALPHA_);
    const float4* w0 = reinterpret_cast<const float4*>(Wp_m + p0 * K_);
    const float4* w1 = reinterpret_cast<const float4*>(Wp_m + p1 * K_);
    float a0 = 0, a1 = 0;
#pragma unroll
    for (int q = 0; q < 4; q++) {
      float4 v0 = w0[q], v1 = w1[q];
      a0 += fabsf(v0.x) + fabsf(v0.y) + fabsf(v0.z) + fabsf(v0.w);
      a1 += fabsf(v1.x) + fabsf(v1.y) + fabsf(v1.z) + fabsf(v1.w);
    }
    wq_m0 = sgn0 * a0 * (1.0f / K_);
    wq_m1 = sgn1 * a1 * (1.0f / K_);
  }
  float gv[8];
  {
    const float4* gp = reinterpret_cast<const float4*>(g2 + tid * 8);
    *reinterpret_cast<float4*>(&gv[0]) = gp[0];
    *reinterpret_cast<float4*>(&gv[4]) = gp[1];
  }
  __syncthreads();  // Sl ready

  // tilde = S @ V (V streamed; proven free under latency-bound regime)
  float til0[G_], til1[G_];
#pragma unroll
  for (int tok = 0; tok < G_; tok++) { til0[tok] = 0; til1[tok] = 0; }
#pragma unroll 8
  for (int rr = 0; rr < R_; rr++) {
    float2 vv = *reinterpret_cast<const float2*>(V + rr * P_ + p0);
#pragma unroll
    for (int tok = 0; tok < G_; tok++) {
      float s = sm.Sl[tok][rr];
      til0[tok] += s * vv.x;
      til1[tok] += s * vv.y;
    }
  }

  // x_after = x + f*tilde*fo_s ; rmsnorm2 -> h (bf16)
  float xa[G_][8];
#pragma unroll
  for (int tok = 0; tok < G_; tok++) {
    size_t trow = (size_t)(token0 + tok);
    const float4* xp = reinterpret_cast<const float4*>(x + trow * D_ + tid * 8);
    float xvv[8];
    *reinterpret_cast<float4*>(&xvv[0]) = xp[0];
    *reinterpret_cast<float4*>(&xvv[4]) = xp[1];
    u32 fp = ftg[trow * 256 + tid];
    float f0 = bfb2f(fp & 0xffffu);
    float f1 = bfb2f(fp >> 16);
    float val0 = f0 * til0[tok] * fo_s0;
    float val1 = f1 * til1[tok] * fo_s1;
    float ss = 0;
#pragma unroll
    for (int a = 0; a < 4; a++) {
      float v0 = xvv[a] + val0;
      float v1 = xvv[4 + a] + val1;
      xa[tok][a] = v0;
      xa[tok][4 + a] = v1;
      ss += v0 * v0 + v1 * v1;
    }
#pragma unroll
    for (int off = 32; off; off >>= 1) ss += __shfl_down(ss, off);
    if ((tid & 63) == 0) sm.red[tok][tid >> 6] = ss;
  }
  __syncthreads();
#pragma unroll
  for (int tok = 0; tok < G_; tok++) {
    float inv = rsqrtf((sm.red[tok][0] + sm.red[tok][1] + sm.red[tok][2] + sm.red[tok][3]) * (1.0f / D_) + EPS_);
    u16 tmp[8];
#pragma unroll
    for (int i = 0; i < 8; i++) tmp[i] = f2bfb(xa[tok][i] * inv * gv[i]);
    *reinterpret_cast<uint4*>(&sm.h[tok * D_ + tid * 8]) = *reinterpret_cast<const uint4*>(tmp);
  }
  // MLP gather weights
  union { int4 v[4]; int s[16]; } iu0, iu1;
  union { float4 v[4]; float s[16]; } wu0, wu1;
  {
    const int4* ip0 = reinterpret_cast<const int4*>(idx_m + p0 * K_);
    const int4* ip1 = reinterpret_cast<const int4*>(idx_m + p1 * K_);
    const float4* wp0 = reinterpret_cast<const float4*>(wg_m + p0 * K_);
    const float4* wp1 = reinterpret_cast<const float4*>(wg_m + p1 * K_);
#pragma unroll
    for (int q = 0; q < 4; q++) { iu0.v[q] = ip0[q]; iu1.v[q] = ip1[q]; wu0.v[q] = wp0[q]; wu1.v[q] = wp1[q]; }
  }
  __syncthreads();

#pragma unroll
  for (int tok = 0; tok < G_; tok++) {
    float a0 = 0, a1 = 0;
#pragma unroll
    for (int k = 0; k < K_; k++) {
      a0 += bfb2f(sm.h[tok * D_ + iu0.s[k]]) * wu0.s[k];
      a1 += bfb2f(sm.h[tok * D_ + iu1.s[k]]) * wu1.s[k];
    }
    float u0 = wq_m0 * a0, u1 = wq_m1 * a1;
    float f0 = sigmoidf_(u0), f1 = sigmoidf_(u1);
    float val0 = f0 * u0 * fo_m0, val1 = f1 * u1 * fo_m1;
    float ov[8];
#pragma unroll
    for (int a = 0; a < 4; a++) {
      ov[a] = xa[tok][a] + val0;
      ov[4 + a] = xa[tok][4 + a] + val1;
    }
    float4* op = reinterpret_cast<float4*>(out + (size_t)(token0 + tok) * D_ + tid * 8);
    op[0] = *reinterpret_cast<const float4*>(&ov[0]);
    op[1] = *reinterpret_cast<const float4*>(&ov[4]);
  }
  __syncthreads();
}

// ---------------- fused cooperative kernel (grid-stride, any grid size) ----------------
__global__ __launch_bounds__(256, 4) void k_fused(
    const float* __restrict__ x, const float* __restrict__ g1,
    const float* __restrict__ g2,
    const int* __restrict__ idx_s, const float* __restrict__ wg_s,
    const int* __restrict__ idx_m, const float* __restrict__ wg_m,
    const float* __restrict__ Wp_s, const float* __restrict__ Wo_s,
    const float* __restrict__ Wp_m, const float* __restrict__ Wo_m,
    const float* __restrict__ U, const float* __restrict__ V,
    const float* __restrict__ Wgt, const float* __restrict__ bg,
    const float* __restrict__ state,
    u32* __restrict__ ftg, float* __restrict__ z, float* __restrict__ lam,
    float* __restrict__ S, float* __restrict__ out, float* __restrict__ out_state) {
  __shared__ SmemU sm;
  cg::grid_group grid = cg::this_grid();
  int tid = threadIdx.x;

  for (int gi = blockIdx.x; gi < NGRP_; gi += gridDim.x)
    phase1_dev(sm.p1, gi, tid, x, g1, idx_s, wg_s, Wp_s, U, Wgt, bg, ftg, z, lam);

  grid.sync();

  for (int br = blockIdx.x; br < B_ * R_; br += gridDim.x)
    scan_dev(br, tid, z, lam, state, S, out_state);

  grid.sync();

  for (int gi = blockIdx.x; gi < NGRP_; gi += gridDim.x)
    phase3_dev(sm.p3, gi, tid, x, g2, idx_m, wg_m, Wo_s, Wp_m, Wo_m, V, S, ftg, out);
}

// ---------------- plain-kernel fallbacks (same device fns) ----------------
__global__ __launch_bounds__(256) void k_p1(
    const float* x, const float* g1, const int* idx_s, const float* wg_s,
    const float* Wp_s, const float* U, const float* Wgt, const float* bg,
    u32* ftg, float* z, float* lam) {
  __shared__ SmemP1 sm;
  phase1_dev(sm, blockIdx.x, threadIdx.x, x, g1, idx_s, wg_s, Wp_s, U, Wgt, bg, ftg, z, lam);
}
__global__ __launch_bounds__(64) void k_scan(
    const float* z, const float* lam, const float* state, float* S, float* out_state) {
  scan_dev(blockIdx.x, threadIdx.x, z, lam, state, S, out_state);
}
__global__ __launch_bounds__(256) void k_p3(
    const float* x, const float* g2, const int* idx_m, const float* wg_m,
    const float* Wo_s, const float* Wp_m, const float* Wo_m, const float* V,
    const float* S, const u32* ftg, float* out) {
  __shared__ SmemP3 sm;
  phase3_dev(sm, blockIdx.x, threadIdx.x, x, g2, idx_m, wg_m, Wo_s, Wp_m, Wo_m, V, S, ftg, out);
}

// ---------------- host ----------------
extern "C" void kernel_launch(void* const* d_in, const int* in_sizes, int n_in,
                              void* d_out, int out_size, void* d_ws, size_t ws_size,
                              hipStream_t stream) {
  const float* x     = (const float*)d_in[0];
  const float* state = (const float*)d_in[1];
  const float* g1    = (const float*)d_in[2];
  const float* g2    = (const float*)d_in[3];
  const int*   idx_s = (const int*)d_in[4];
  const float* wg_s  = (const float*)d_in[5];
  const int*   idx_m = (const int*)d_in[6];
  const float* wg_m  = (const float*)d_in[7];
  const float* Wp_s  = (const float*)d_in[8];
  const float* Wo_s  = (const float*)d_in[9];
  const float* Wp_m  = (const float*)d_in[10];
  const float* Wo_m  = (const float*)d_in[11];
  const float* U     = (const float*)d_in[12];
  const float* V     = (const float*)d_in[13];
  const float* Wgt   = (const float*)d_in[14];
  const float* bg    = (const float*)d_in[15];
  float* out = (float*)d_out;
  float* out_state = out + (size_t)B_ * T_ * D_;

  char* ws = (char*)d_ws;
  float* z   = (float*)ws;                                      // 1 MB
  float* lam = (float*)(ws + (size_t)(1 << 20));                // 1 MB
  float* S   = (float*)(ws + (size_t)(2 << 20));                // 1 MB
  u32* ftg   = (u32*)(ws + (size_t)(3 << 20));                  // 8 MB

  // driver-computed co-residency -> guaranteed-valid cooperative grid
  int occ = 0;
  hipError_t qe = hipOccupancyMaxActiveBlocksPerMultiprocessor(&occ, k_fused, 256, 0);
  int grid = (qe == hipSuccess && occ > 0) ? occ * 256 : 0;
  if (grid > NGRP_) grid = NGRP_;

  hipError_t le = hipErrorUnknown;
  if (grid > 0) {
    void* args[] = {
        (void*)&x, (void*)&g1, (void*)&g2, (void*)&idx_s, (void*)&wg_s,
        (void*)&idx_m, (void*)&wg_m, (void*)&Wp_s, (void*)&Wo_s,
        (void*)&Wp_m, (void*)&Wo_m, (void*)&U, (void*)&V, (void*)&Wgt,
        (void*)&bg, (void*)&state, (void*)&ftg, (void*)&z, (void*)&lam,
        (void*)&S, (void*)&out, (void*)&out_state};
    le = hipLaunchCooperativeKernel(k_fused, dim3(grid), dim3(256), args, 0, stream);
  }
  if (le != hipSuccess) {
    // fallback: identical math as 3 plain launches
    hipLaunchKernelGGL(k_p1, dim3(NGRP_), dim3(256), 0, stream,
                       x, g1, idx_s, wg_s, Wp_s, U, Wgt, bg, ftg, z, lam);
    hipLaunchKernelGGL(k_scan, dim3(B_ * R_), dim3(64), 0, stream,
                       z, lam, state, S, out_state);
    hipLaunchKernelGGL(k_p3, dim3(NGRP_), dim3(256), 0, stream,
                       x, g2, idx_m, wg_m, Wo_s, Wp_m, Wo_m, V, S, ftg, out);
  }
}